// Round 4
// baseline (3508.198 us; speedup 1.0000x reference)
//
#include <hip/hip_runtime.h>
#include <stdint.h>

#define BSIZE 1024
#define DIM   16384
#define HID   1024
#define TAIL  ((size_t)960 * DIM)   /* h region start (floats) in d_out */

// ---------------- threefry2x32 (JAX-compatible, 20 rounds) ----------------
__device__ __forceinline__ void tf2x32(uint32_t k0, uint32_t k1,
                                       uint32_t x0, uint32_t x1,
                                       uint32_t& o0, uint32_t& o1) {
  const uint32_t ks2 = k0 ^ k1 ^ 0x1BD11BDAu;
#define TFR(r) { x0 += x1; x1 = (x1 << r) | (x1 >> (32 - r)); x1 ^= x0; }
  x0 += k0; x1 += k1;
  TFR(13) TFR(15) TFR(26) TFR(6)
  x0 += k1;  x1 += ks2 + 1u;
  TFR(17) TFR(29) TFR(16) TFR(24)
  x0 += ks2; x1 += k0 + 2u;
  TFR(13) TFR(15) TFR(26) TFR(6)
  x0 += k0;  x1 += k1 + 3u;
  TFR(17) TFR(29) TFR(16) TFR(24)
  x0 += k1;  x1 += ks2 + 4u;
  TFR(13) TFR(15) TFR(26) TFR(6)
  x0 += ks2; x1 += k0 + 5u;
#undef TFR
  o0 = x0; o1 = x1;
}

__device__ __forceinline__ float bits_to_unit_float(uint32_t bits) {
  return __uint_as_float((bits >> 9) | 0x3f800000u) - 1.0f;
}

__device__ __forceinline__ float bits_to_gumbel(uint32_t bits) {
  float u = bits_to_unit_float(bits);
  if (u == 0.0f) u = 1.1754943508222875e-38f;   // minval = finfo(f32).tiny
  float l1 = (float)log((double)u);
  float nl1 = -l1;
  float l2 = (float)log((double)nl1);
  return -l2;
}

__device__ __forceinline__ double softplus_d(double z) {
  return (z > 0.0) ? (z + log1p(exp(-z))) : log1p(exp(z));
}

// ---------------- K1: h = x @ W + bh  (h -> d_out tail) ----------------
__global__ __launch_bounds__(256) void gemm_h_kernel(
    const float* __restrict__ x, const float* __restrict__ W,
    const float* __restrict__ bh, float* __restrict__ hbuf) {
  __shared__ float Al[32][64];
  __shared__ float Bl[32][64];
  const int tid = threadIdx.x;
  const int n0 = blockIdx.x * 64;
  const int m0 = blockIdx.y * 64;
  const int arow = tid >> 2, ak = (tid & 3) * 8;
  const int bk = tid >> 3, bn = (tid & 7) * 8;
  const int ty = tid >> 4, tx = tid & 15;

  float acc[4][4];
  for (int i = 0; i < 4; ++i)
    for (int j = 0; j < 4; ++j) acc[i][j] = 0.0f;

  for (int kt = 0; kt < DIM / 32; ++kt) {
    const int k0 = kt * 32;
    const float* ap = x + (size_t)(m0 + arow) * DIM + k0 + ak;
    float4 av0 = *(const float4*)(ap + 0);
    float4 av1 = *(const float4*)(ap + 4);
    const float* bp = W + (size_t)(k0 + bk) * HID + n0 + bn;
    float4 bv0 = *(const float4*)(bp + 0);
    float4 bv1 = *(const float4*)(bp + 4);
    __syncthreads();
    {
      float ta[8] = {av0.x, av0.y, av0.z, av0.w, av1.x, av1.y, av1.z, av1.w};
      for (int e = 0; e < 8; ++e) Al[ak + e][arow] = ta[e];
    }
    *(float4*)&Bl[bk][bn + 0] = bv0;
    *(float4*)&Bl[bk][bn + 4] = bv1;
    __syncthreads();
#pragma unroll 8
    for (int k = 0; k < 32; ++k) {
      const float4 a4 = *(const float4*)&Al[k][ty * 4];
      const float4 b4 = *(const float4*)&Bl[k][tx * 4];
      const float a[4] = {a4.x, a4.y, a4.z, a4.w};
      const float b[4] = {b4.x, b4.y, b4.z, b4.w};
      for (int i = 0; i < 4; ++i)
        for (int j = 0; j < 4; ++j)
          acc[i][j] = fmaf(a[i], b[j], acc[i][j]);
    }
  }
  for (int i = 0; i < 4; ++i) {
    const int gm = m0 + ty * 4 + i;
    for (int j = 0; j < 4; ++j) {
      const int gn = n0 + tx * 4 + j;
      hbuf[(size_t)gm * HID + gn] = acc[i][j] + bh[gn];
    }
  }
}

// ------- K1b: stash h rows 960..1023 (65536 floats) into d_ws -------
__global__ __launch_bounds__(256) void copy_stash_kernel(
    const float* __restrict__ src, float* __restrict__ dst) {
  const int i = blockIdx.x * 256 + threadIdx.x;
  ((float4*)dst)[i] = ((const float4*)src)[i];
}

// -- K2: s rows = (1-2x)*(sigmoid(h) @ W^T + c)*0.5. M-tile 64, N-tile 128 --
__global__ __launch_bounds__(256) void gemm2_kernel(
    const float* __restrict__ h_src,   // rows indexed LOCALLY
    const float* __restrict__ W, const float* __restrict__ c,
    const float* __restrict__ x,       // rows indexed GLOBALLY
    float* __restrict__ s_dst,         // rows indexed LOCALLY, stride DIM
    int m_start) {
  __shared__ float Al[32][64];
  __shared__ float Bl[32][128];
  const int tid = threadIdx.x;
  const int m0l = blockIdx.x * 64;
  const int n0  = blockIdx.y * 128;
  const int arow = tid >> 2, ak = (tid & 3) * 8;
  const int nrow = tid >> 1, kof = (tid & 1) * 16;
  const int ty = tid >> 4, tx = tid & 15;

  float acc[4][8];
  for (int i = 0; i < 4; ++i)
    for (int j = 0; j < 8; ++j) acc[i][j] = 0.0f;

  for (int kt = 0; kt < HID / 32; ++kt) {
    const int k0 = kt * 32;
    const float* ap = h_src + (size_t)(m0l + arow) * HID + k0 + ak;
    float4 av0 = *(const float4*)(ap + 0);
    float4 av1 = *(const float4*)(ap + 4);
    const float* bp = W + (size_t)(n0 + nrow) * HID + k0 + kof;
    float4 bv0 = *(const float4*)(bp + 0);
    float4 bv1 = *(const float4*)(bp + 4);
    float4 bv2 = *(const float4*)(bp + 8);
    float4 bv3 = *(const float4*)(bp + 12);
    __syncthreads();
    {
      float ta[8] = {av0.x, av0.y, av0.z, av0.w, av1.x, av1.y, av1.z, av1.w};
      for (int e = 0; e < 8; ++e)
        Al[ak + e][arow] = (float)(1.0 / (1.0 + exp(-(double)ta[e])));
      float tb[16] = {bv0.x,bv0.y,bv0.z,bv0.w, bv1.x,bv1.y,bv1.z,bv1.w,
                      bv2.x,bv2.y,bv2.z,bv2.w, bv3.x,bv3.y,bv3.z,bv3.w};
      for (int e = 0; e < 16; ++e) Bl[kof + e][nrow] = tb[e];
    }
    __syncthreads();
#pragma unroll 4
    for (int k = 0; k < 32; ++k) {
      const float4 a4 = *(const float4*)&Al[k][ty * 4];
      const float4 b0 = *(const float4*)&Bl[k][tx * 8];
      const float4 b1 = *(const float4*)&Bl[k][tx * 8 + 4];
      const float a[4]  = {a4.x, a4.y, a4.z, a4.w};
      const float bb[8] = {b0.x,b0.y,b0.z,b0.w, b1.x,b1.y,b1.z,b1.w};
      for (int i = 0; i < 4; ++i)
        for (int j = 0; j < 8; ++j)
          acc[i][j] = fmaf(a[i], bb[j], acc[i][j]);
    }
  }
  for (int i = 0; i < 4; ++i) {
    const int gml = m0l + ty * 4 + i;
    const size_t xoff = (size_t)(m_start + gml) * DIM + n0 + tx * 8;
    const size_t soff = (size_t)gml * DIM + n0 + tx * 8;
    for (int q = 0; q < 2; ++q) {
      float4 xv = *(const float4*)(x + xoff + q * 4);
      float4 cv = *(const float4*)(c + n0 + tx * 8 + q * 4);
      float g0 = acc[i][q * 4 + 0] + cv.x;
      float g1 = acc[i][q * 4 + 1] + cv.y;
      float g2 = acc[i][q * 4 + 2] + cv.z;
      float g3 = acc[i][q * 4 + 3] + cv.w;
      float4 sv;
      sv.x = ((xv.x == 1.0f) ? -g0 : g0) * 0.5f;
      sv.y = ((xv.y == 1.0f) ? -g1 : g1) * 0.5f;
      sv.z = ((xv.z == 1.0f) ? -g2 : g2) * 0.5f;
      sv.w = ((xv.w == 1.0f) ? -g3 : g3) * 0.5f;
      *(float4*)(s_dst + soff + q * 4) = sv;
    }
  }
}

// ------- K3: per-row scan + accept. s row lives in REGISTERS (sv[32]). -------
// LDS: 328 bytes total. All sv[] accesses statically indexed (rule #20).
__global__ __launch_bounds__(512) void row_kernel(
    const float* __restrict__ x, const float* __restrict__ W,
    const float* __restrict__ c, const int* __restrict__ radius,
    const float* __restrict__ h_base,   // + lb*HID
    const float* __restrict__ s_base,   // + lb*DIM
    float* __restrict__ out, int b0) {
  const int lb = blockIdx.x;
  const int b  = b0 + lb;
  const int tid = threadIdx.x;

  __shared__ float  red_v[8];
  __shared__ int    red_i[8];
  __shared__ double red_d[8];
  __shared__ int    diff[16];
  __shared__ float  sgn_sh[16];
  __shared__ float  sflip[16];
  __shared__ int    diff_cnt;
  __shared__ int    accept_flag;

  if (tid == 0) diff_cnt = 0;

  // s row -> registers: global index d = tid + i*512 (owner: tid = d & 511)
  float sv[32];
#pragma unroll
  for (int i = 0; i < 32; ++i)
    sv[i] = s_base[(size_t)lb * DIM + tid + i * 512];

  auto block_lse = [&]() -> double {
    float mloc = sv[0];
#pragma unroll
    for (int i = 1; i < 32; ++i) mloc = fmaxf(mloc, sv[i]);
    for (int o = 32; o; o >>= 1) mloc = fmaxf(mloc, __shfl_xor(mloc, o));
    if ((tid & 63) == 0) red_v[tid >> 6] = mloc;
    __syncthreads();
    const float m = fmaxf(fmaxf(fmaxf(red_v[0], red_v[1]), fmaxf(red_v[2], red_v[3])),
                          fmaxf(fmaxf(red_v[4], red_v[5]), fmaxf(red_v[6], red_v[7])));
    double ssum = 0.0;
#pragma unroll
    for (int i = 0; i < 32; ++i) ssum += exp((double)sv[i] - (double)m);
    for (int o = 32; o; o >>= 1) ssum += __shfl_xor(ssum, o);
    if ((tid & 63) == 0) red_d[tid >> 6] = ssum;
    __syncthreads();
    double tot = ((red_d[0] + red_d[1]) + (red_d[2] + red_d[3])) +
                 ((red_d[4] + red_d[5]) + (red_d[6] + red_d[7]));
    __syncthreads();
    return log(tot) + (double)m;
  };

  const double logZx = block_lse();

  int r = radius[b];
  if (r < 0) r = 0;
  if (r > 15) r = 15;
  const uint32_t jbase = (uint32_t)(b * DIM);

  for (int t = 0; t < r; ++t) {
    uint32_t kt0, kt1;
    tf2x32(0u, 42u, 0u, (uint32_t)t, kt0, kt1);   // fold_in(key(42), t)
    float bestv;
    int   besti;
    {
      uint32_t o0, o1;
      tf2x32(kt0, kt1, 0u, jbase + (uint32_t)tid, o0, o1);
      bestv = bits_to_gumbel(o0 ^ o1) + sv[0];
      besti = tid;
    }
#pragma unroll
    for (int i = 1; i < 32; ++i) {
      const int d = tid + i * 512;
      uint32_t o0, o1;
      tf2x32(kt0, kt1, 0u, jbase + (uint32_t)d, o0, o1);  // partitionable ctr (0,j)
      const float val = bits_to_gumbel(o0 ^ o1) + sv[i];
      if (val > bestv) { bestv = val; besti = d; }
    }
    for (int o = 32; o; o >>= 1) {
      const float ov = __shfl_xor(bestv, o);
      const int   oi = __shfl_xor(besti, o);
      if (ov > bestv || (ov == bestv && oi < besti)) { bestv = ov; besti = oi; }
    }
    if ((tid & 63) == 0) { red_v[tid >> 6] = bestv; red_i[tid >> 6] = besti; }
    __syncthreads();
    // every thread computes the identical block winner
    float bv = red_v[0]; int bi = red_i[0];
    for (int w = 1; w < 8; ++w)
      if (red_v[w] > bv || (red_v[w] == bv && red_i[w] < bi)) { bv = red_v[w]; bi = red_i[w]; }
    // owner flips its register copy (static-index unroll)
    if ((bi & 511) == tid) {
      const int slot = bi >> 9;
#pragma unroll
      for (int i = 0; i < 32; ++i) if (i == slot) sv[i] = -sv[i];
    }
    if (tid == 0) {
      int found = -1;
      for (int j = 0; j < diff_cnt; ++j) if (diff[j] == bi) found = j;
      if (found >= 0) { diff[found] = diff[diff_cnt - 1]; diff_cnt -= 1; }
      else { diff[diff_cnt] = bi; diff_cnt += 1; }
    }
    __syncthreads();   // protects red_v/red_i reuse and diff updates
  }

  const double lse_y = block_lse();

  const int dc_n = diff_cnt;
  // publish flipped s values (owners write; uniform j-loop)
  for (int j = 0; j < dc_n; ++j) {
    const int d = diff[j];
    if ((d & 511) == tid) {
      const int slot = d >> 9;
#pragma unroll
      for (int i = 0; i < 32; ++i) if (i == slot) sflip[j] = sv[i];
    }
  }
  if (tid < dc_n) sgn_sh[tid] = 1.0f - 2.0f * x[(size_t)b * DIM + diff[tid]];
  __syncthreads();

  double dsp = 0.0;
  for (int rep = 0; rep < 2; ++rep) {
    const int hh = tid + rep * 512;
    const float hxv = h_base[(size_t)lb * HID + hh];
    double delta = 0.0;
    for (int j = 0; j < dc_n; ++j)
      delta += (double)sgn_sh[j] * (double)W[(size_t)diff[j] * HID + hh];
    if (dc_n > 0) {
      const double hx = (double)hxv;
      dsp += softplus_d(hx + delta) - softplus_d(hx);
    }
  }
  for (int o = 32; o; o >>= 1) dsp += __shfl_xor(dsp, o);
  if ((tid & 63) == 0) red_d[tid >> 6] = dsp;
  __syncthreads();

  if (tid == 0) {
    const double dsp_tot = ((red_d[0] + red_d[1]) + (red_d[2] + red_d[3])) +
                           ((red_d[4] + red_d[5]) + (red_d[6] + red_d[7]));
    double dc = 0.0, ltilde = 0.0;
    for (int j = 0; j < dc_n; ++j) {
      dc += (double)sgn_sh[j] * (double)c[diff[j]];
      ltilde += 2.0 * (double)sflip[j];   // s_y at flipped coords
    }
    double la = (dsp_tot + dc) + ltilde + (logZx - lse_y);
    if (la > 0.0) la = 0.0;
    const double p = exp(la);
    uint32_t ku0, ku1, o0, o1;
    tf2x32(0u, 42u, 0u, 16u, ku0, ku1);          // fold_in(key(42), 16)
    tf2x32(ku0, ku1, 0u, (uint32_t)b, o0, o1);   // partitionable ctr (0, b)
    const float ub = bits_to_unit_float(o0 ^ o1);
    accept_flag = (p >= (double)ub) ? 1 : 0;
  }
  __syncthreads();

  {
    const float4* xr = (const float4*)(x + (size_t)b * DIM);
    float4* orow = (float4*)(out + (size_t)b * DIM);
    for (int i = 0; i < DIM / 4 / 512; ++i)
      orow[i * 512 + tid] = xr[i * 512 + tid];
  }
  __syncthreads();
  if (accept_flag && tid < dc_n) {
    const int d = diff[tid];
    out[(size_t)b * DIM + d] = 1.0f - x[(size_t)b * DIM + d];
  }
}

// ---------------- launch ----------------
extern "C" void kernel_launch(void* const* d_in, const int* in_sizes, int n_in,
                              void* d_out, int out_size, void* d_ws, size_t ws_size,
                              hipStream_t stream) {
  const float* x      = (const float*)d_in[0];
  const float* W      = (const float*)d_in[1];
  const float* bh     = (const float*)d_in[2];
  const float* c      = (const float*)d_in[3];
  const int*   radius = (const int*)d_in[4];
  float* out = (float*)d_out;

  if (ws_size < (size_t)64 * HID * sizeof(float)) return;  // fast-fail, not fault
  float* stash = (float*)d_ws;

  float* h_tail = out + TAIL;

  dim3 g1(HID / 64, BSIZE / 64);
  gemm_h_kernel<<<g1, 256, 0, stream>>>(x, W, bh, h_tail);

  copy_stash_kernel<<<64, 256, 0, stream>>>(h_tail + (size_t)960 * HID, stash);

  dim3 g2a(960 / 64, DIM / 128);
  gemm2_kernel<<<g2a, 256, 0, stream>>>(h_tail, W, c, x, out, 0);

  row_kernel<<<960, 512, 0, stream>>>(x, W, c, radius, h_tail, out, out, 0);

  dim3 g2b(1, DIM / 128);
  gemm2_kernel<<<g2b, 256, 0, stream>>>(stash, W, c, x, out + TAIL, 960);

  row_kernel<<<64, 512, 0, stream>>>(x, W, c, radius, stash, out + TAIL, out, 960);
}